// Round 5
// baseline (325.208 us; speedup 1.0000x reference)
//
#include <hip/hip_runtime.h>
#include <stdint.h>

typedef __attribute__((ext_vector_type(4))) float          f32x4;
typedef __attribute__((ext_vector_type(8))) short          bf16x8;
typedef __attribute__((ext_vector_type(8))) unsigned short u16x8;
typedef __attribute__((ext_vector_type(4))) unsigned short u16x4;

static __device__ __forceinline__ unsigned short f2bf(float f){
  uint32_t u = __builtin_bit_cast(uint32_t, f);
  u += 0x7FFFu + ((u >> 16) & 1u);          // RNE
  return (unsigned short)(u >> 16);
}
static __device__ __forceinline__ float bf2f(unsigned short h){
  uint32_t u = ((uint32_t)h) << 16;
  return __builtin_bit_cast(float, u);
}

// ---------------- elementwise convert f32 -> bf16 (8/thread) ----------------
__global__ void k_cvt(const float* __restrict__ in, unsigned short* __restrict__ out, long n){
  long i = ((long)blockIdx.x * blockDim.x + threadIdx.x) * 8;
  if (i >= n) return;
  const f32x4* p = (const f32x4*)(in + i);
  f32x4 a = p[0], b = p[1];
  u16x8 o;
  #pragma unroll
  for (int j = 0; j < 4; j++){ o[j] = f2bf(a[j]); o[4+j] = f2bf(b[j]); }
  *(u16x8*)(out + i) = o;
}

// ---------------- tiled transpose+convert: in[R][C] f32 -> out[C][R] bf16 ----
__global__ void k_tconv(const float* __restrict__ in, unsigned short* __restrict__ out, int R, int C){
  __shared__ float tl[64][65];
  const int c0 = blockIdx.x * 64, r0 = blockIdx.y * 64;
  const int t = threadIdx.x;
  {
    const int lr = t >> 2, lc = (t & 3) * 16;
    const f32x4* s = (const f32x4*)(in + (long)(r0 + lr) * C + c0 + lc);
    #pragma unroll
    for (int q = 0; q < 4; q++){
      f32x4 v = s[q];
      #pragma unroll
      for (int j = 0; j < 4; j++) tl[lr][lc + q*4 + j] = v[j];
    }
  }
  __syncthreads();
  {
    const int oc = t >> 2, orr = (t & 3) * 16;
    u16x8 o0, o1;
    #pragma unroll
    for (int i = 0; i < 8; i++){ o0[i] = f2bf(tl[orr + i][oc]); o1[i] = f2bf(tl[orr + 8 + i][oc]); }
    u16x8* dst = (u16x8*)(out + (long)(c0 + oc) * R + r0 + orr);
    dst[0] = o0; dst[1] = o1;
  }
}

// ================= 256x256 merged-4-phase counted-vmcnt GEMM =================
// Phase = {12 ds_read_b128; 2 stage2; bar; lgkm(0); 32 MFMA; [gate]; bar}.
// 4 phases per 2 K-tiles (half the barrier count of the 8-phase form).
// Stage rotation (slot freed one phase before): P00:t1.A1B1  P01:t2.A0B0
// P10:t2.A1B1  P11:t3.A0B0.  Gates vmcnt(4) at P01/P11; vmcnt(0) last iter.

static __device__ __forceinline__ void stage2(const unsigned short* __restrict__ G, int row0, int ke,
                                              char* lds_slot, int t){
  #pragma unroll
  for (int l = 0; l < 2; l++){
    const int r  = l*128 + (t >> 2);
    const int ko = (t & 3) ^ ((r ^ (r >> 2)) & 3);
    const char* src = (const char*)(G + (long)(row0 + r) * 768 + ke + ko * 8);
    char* dst = lds_slot + l*8192 + (t & 0x1C0) * 16;          // wave-uniform base
    __builtin_amdgcn_global_load_lds((const __attribute__((address_space(1))) unsigned int*)src,
                                     (__attribute__((address_space(3))) unsigned int*)dst, 16, 0, 0);
  }
}

static __device__ __forceinline__ bf16x8 ldfrag(const char* slot, int row, int ko){
  const int k2 = (ko ^ (row ^ (row >> 2))) & 3;
  return *(const bf16x8*)(slot + row*64 + k2*16);
}

#define GATE { if (it == 5) asm volatile("s_waitcnt vmcnt(0)" ::: "memory");   \
               else         asm volatile("s_waitcnt vmcnt(4)" ::: "memory"); }

#define PHASE4(BUF, KK, STAGE_STMT, WAIT_STMT) do {                            \
    bf16x8 af[8], bq[4];                                                       \
    _Pragma("unroll")                                                          \
    for (int ni = 0; ni < 4; ni++)                                             \
      bq[ni] = ldfrag(sB[BUF][KK], wn*64 + ni*16 + arow, ko);                  \
    _Pragma("unroll")                                                          \
    for (int mi = 0; mi < 8; mi++)                                             \
      af[mi] = ldfrag(sA[BUF][KK], wm*128 + mi*16 + arow, ko);                 \
    STAGE_STMT;                                                                \
    __builtin_amdgcn_sched_barrier(0);                                         \
    __builtin_amdgcn_s_barrier();                                              \
    asm volatile("s_waitcnt lgkmcnt(0)" ::: "memory");                         \
    __builtin_amdgcn_sched_barrier(0);                                         \
    __builtin_amdgcn_s_setprio(1);                                             \
    _Pragma("unroll")                                                          \
    for (int mi = 0; mi < 8; mi++)                                             \
      _Pragma("unroll")                                                        \
      for (int ni = 0; ni < 4; ni++)                                           \
        acc[mi][ni] = __builtin_amdgcn_mfma_f32_16x16x32_bf16(                 \
            af[mi], bq[ni], acc[mi][ni], 0, 0, 0);                             \
    __builtin_amdgcn_s_setprio(0);                                             \
    __builtin_amdgcn_sched_barrier(0);                                         \
    WAIT_STMT;                                                                 \
    __builtin_amdgcn_s_barrier();                                              \
  } while(0)

// MODE 0: A=x_bf[32768][768], BT=WT[2304][768] -> QT/KT (transposed) + V + nrmp
// MODE 1: A=V[32768][768], BT=WmodT[8][768][768] (batched) -> OUTF fp32 + bias
template<int MODE>
__global__ __launch_bounds__(512, 2)
void k_gemm2(const unsigned short* __restrict__ A, const unsigned short* __restrict__ BT,
             unsigned short* __restrict__ QT, unsigned short* __restrict__ KT,
             unsigned short* __restrict__ V, float* __restrict__ OUTF,
             const float* __restrict__ bias, float* __restrict__ nrmp)
{
  __shared__ __attribute__((aligned(16))) char lds[131072];
  const int o = blockIdx.x;
  int mt, jt;
  if (MODE == 0){
    // per-XCD chunks of 2mt x 9jt (working set ~4.3MB ~ L2)
    const int xcd = o & 7, i = o >> 3;        // i in [0,144)
    const int mb = i / 18, r = i - mb * 18;
    jt = r >> 1; mt = xcd * 16 + mb * 2 + (r & 1);
  } else {
    // per-XCD chunks of 4mt x 3jt (working set ~2.7MB, B_b fits L2)
    const int xcd = o & 7, i = o >> 3;        // i in [0,48)
    const int mb = i / 12, r = i - mb * 12;
    jt = r >> 2; mt = xcd * 16 + mb * 4 + (r & 3);
  }
  const int m0 = mt * 256, j0 = jt * 256;
  const int t = threadIdx.x, lane = t & 63, w = t >> 6;
  const int wm = w >> 2, wn = w & 3;
  const int arow = lane & 15, ko = lane >> 4;
  const unsigned short* BTb = (MODE == 1) ? BT + ((long)(m0 >> 12)) * 768 * 768 : BT;

  char* const sA[2][2] = {{lds,           lds + 16384},
                          {lds + 65536,   lds + 65536 + 16384}};
  char* const sB[2][2] = {{lds + 32768,   lds + 49152},
                          {lds + 65536 + 32768, lds + 65536 + 49152}};

  f32x4 acc[8][4] = {};

  // prologue: T0 fully + T1 kk0 slots (12 loads); vmcnt(4) completes T0
  stage2(A,   m0, 0,   sA[0][0], t);  stage2(BTb, j0, 0,   sB[0][0], t);
  stage2(A,   m0, 32,  sA[0][1], t);  stage2(BTb, j0, 32,  sB[0][1], t);
  stage2(A,   m0, 64,  sA[1][0], t);  stage2(BTb, j0, 64,  sB[1][0], t);
  asm volatile("s_waitcnt vmcnt(4)" ::: "memory");
  __builtin_amdgcn_s_barrier();

  #pragma unroll 1
  for (int it = 0; it < 6; ++it){
    const int t1 = 2*it + 1, t2 = 2*it + 2, t3 = 2*it + 3;
    PHASE4(0,0, { stage2(A, m0, t1*64+32, sA[1][1], t);
                  stage2(BTb, j0, t1*64+32, sB[1][1], t); }, ;);
    PHASE4(0,1, { if (t2 < 12){ stage2(A, m0, t2*64, sA[0][0], t);
                                stage2(BTb, j0, t2*64, sB[0][0], t); } }, GATE);
    PHASE4(1,0, { if (t2 < 12){ stage2(A, m0, t2*64+32, sA[0][1], t);
                                stage2(BTb, j0, t2*64+32, sB[0][1], t); } }, ;);
    PHASE4(1,1, { if (t3 < 12){ stage2(A, m0, t3*64, sA[1][0], t);
                                stage2(BTb, j0, t3*64, sB[1][0], t); } }, GATE);
  }

  if (MODE == 0){
    const int b = m0 >> 12;
    if (j0 < 1536){
      const int nb = (m0 & 4095) + wm*128 + (lane >> 4)*4;
      #pragma unroll
      for (int mi = 0; mi < 8; mi++){
        #pragma unroll
        for (int ni = 0; ni < 4; ni++){
          const int jc = j0 + wn*64 + ni*16 + (lane & 15);
          const int s  = (jc >= 768);
          const int jl = jc - s * 768;
          const int h  = jl / 48;
          const int c  = jl - h * 48;
          unsigned short* dst = (s ? KT : QT) + (((long)(b*16 + h) * 48 + c) << 12) + nb + mi*16;
          u16x4 pk;
          #pragma unroll
          for (int r = 0; r < 4; r++) pk[r] = f2bf(acc[mi][ni][r]);
          *(u16x4*)dst = pk;
        }
      }
      // deterministic per-(row, 128-chunk) sum-of-squares partials (fp32, pre-bf16)
      const int chunk = ((m0 & 4095) >> 7) + wm;   // 32 chunks of 128 per batch-row
      #pragma unroll
      for (int ni = 0; ni < 4; ni++){
        float ss = 0.f;
        #pragma unroll
        for (int mi = 0; mi < 8; mi++)
          #pragma unroll
          for (int r = 0; r < 4; r++) ss += acc[mi][ni][r] * acc[mi][ni][r];
        ss += __shfl_xor(ss, 16);
        ss += __shfl_xor(ss, 32);
        if (lane < 16){
          const int jc = j0 + wn*64 + ni*16 + lane;
          const int s  = (jc >= 768);
          const int jl = jc - s * 768;
          const int h  = jl / 48;
          const int c  = jl - h * 48;
          const int prow = s*6144 + (b*16 + h)*48 + c;
          nrmp[(long)prow*32 + chunk] = ss;
        }
      }
    } else {
      #pragma unroll
      for (int mi = 0; mi < 8; mi++){
        #pragma unroll
        for (int ni = 0; ni < 4; ni++){
          const int jv = (j0 - 1536) + wn*64 + ni*16 + (lane & 15);
          const long mr = (long)m0 + wm*128 + mi*16 + (lane >> 4)*4;
          #pragma unroll
          for (int r = 0; r < 4; r++) V[(mr + r) * 768 + jv] = f2bf(acc[mi][ni][r]);
        }
      }
    }
  } else {
    #pragma unroll
    for (int mi = 0; mi < 8; mi++){
      #pragma unroll
      for (int ni = 0; ni < 4; ni++){
        const int jc = j0 + wn*64 + ni*16 + (lane & 15);
        const float bv = bias[jc];
        const long mr = (long)m0 + wm*128 + mi*16 + (lane >> 4)*4;
        #pragma unroll
        for (int r = 0; r < 4; r++) OUTF[(mr + r) * 768 + jc] = acc[mi][ni][r] + bv;
      }
    }
  }
}

// ---------------- S partials: per (bh, ksp) 48x48 over 1024 n ---------------
__global__ __launch_bounds__(256)
void k_attn_part(const unsigned short* __restrict__ QT, const unsigned short* __restrict__ KT,
                 float* __restrict__ Spart)
{
  __shared__ float Sl[4][2304];
  const int bh = blockIdx.x, ksp = blockIdx.y;
  const int t = threadIdx.x, lane = t & 63, w = t >> 6;
  const unsigned short* qb = QT + ((long)bh * 48 << 12);
  const unsigned short* kb = KT + ((long)bh * 48 << 12);
  const int n00 = ksp * 1024 + w * 256;
  f32x4 acc[3][3] = {};
  for (int kt = 0; kt < 256; kt += 32){
    bf16x8 af[3], bfr[3];
    #pragma unroll
    for (int ci = 0; ci < 3; ci++)
      af[ci]  = *(const bf16x8*)(qb + ((long)(ci*16 + (lane & 15)) << 12) + n00 + kt + (lane >> 4) * 8);
    #pragma unroll
    for (int di = 0; di < 3; di++)
      bfr[di] = *(const bf16x8*)(kb + ((long)(di*16 + (lane & 15)) << 12) + n00 + kt + (lane >> 4) * 8);
    #pragma unroll
    for (int ci = 0; ci < 3; ci++)
      #pragma unroll
      for (int di = 0; di < 3; di++)
        acc[ci][di] = __builtin_amdgcn_mfma_f32_16x16x32_bf16(af[ci], bfr[di], acc[ci][di], 0, 0, 0);
  }
  #pragma unroll
  for (int ci = 0; ci < 3; ci++)
    #pragma unroll
    for (int di = 0; di < 3; di++)
      #pragma unroll
      for (int r = 0; r < 4; r++)
        Sl[w][(ci*16 + (lane >> 4)*4 + r) * 48 + di*16 + (lane & 15)] = acc[ci][di][r];
  __syncthreads();
  float* outp = Spart + ((long)ksp * 128 + bh) * 2304;
  for (int idx = t; idx < 2304; idx += 256)
    outp[idx] = Sl[0][idx] + Sl[1][idx] + Sl[2][idx] + Sl[3][idx];
}

// --- reduce partials + norms, scale, softmax -> attnT bf16 [bh][48 d][64 c] --
__global__ void k_softmax(const float* __restrict__ Spart, const float* __restrict__ nrmp,
                          const float* __restrict__ temp, unsigned short* __restrict__ attnT)
{
  __shared__ float invq[48], invk[48];
  const int bh = blockIdx.x, h = bh & 15;
  const int c = threadIdx.x;   // 64 threads, 48 active
  if (c < 48){
    float sq = 0.f, sk = 0.f;
    const float* pq = nrmp + (long)(bh*48 + c) * 32;
    const float* pk = nrmp + (long)(6144 + bh*48 + c) * 32;
    #pragma unroll
    for (int i = 0; i < 32; i++){ sq += pq[i]; sk += pk[i]; }
    invq[c] = 1.0f / fmaxf(sqrtf(sq), 1e-12f);
    invk[c] = 1.0f / fmaxf(sqrtf(sk), 1e-12f);
  }
  __syncthreads();
  if (c < 48){
    const float scq = invq[c] * temp[h];
    float row[48];
    #pragma unroll
    for (int d = 0; d < 48; d++){
      long base = ((long)bh * 48 + c) * 48 + d;
      float v = Spart[base] + Spart[base + 128L*2304] + Spart[base + 256L*2304] + Spart[base + 384L*2304];
      row[d] = v * scq * invk[d];
    }
    float mx = -1e30f;
    #pragma unroll
    for (int d = 0; d < 48; d++) mx = fmaxf(mx, row[d]);
    float s = 0.f;
    #pragma unroll
    for (int d = 0; d < 48; d++){ row[d] = expf(row[d] - mx); s += row[d]; }
    const float inv = 1.0f / s;
    unsigned short* ob = attnT + (long)bh * 48 * 64;
    // transposed write: thread c fills column c of [48 d][64 c] tile
    #pragma unroll
    for (int d = 0; d < 48; d++) ob[d*64 + c] = f2bf(row[d] * inv);
    // zero-pad cols 48..63 of row d=c (K=64 padding for wmod MFMA)
    u16x8 z = {};
    *(u16x8*)(ob + c*64 + 48) = z;
    *(u16x8*)(ob + c*64 + 56) = z;
  }
}

// --- WmodT[b][j][h*48+d] = sum_c attnT[bh][d][c] * WpT[j][h*48+c] (MFMA) -----
__global__ __launch_bounds__(256)
void k_wmod2(const unsigned short* __restrict__ WpT, const unsigned short* __restrict__ attnT,
             unsigned short* __restrict__ WmodT)
{
  const int j0 = blockIdx.x * 256, h = blockIdx.y, b = blockIdx.z;
  const int t = threadIdx.x, lane = t & 63, w = t >> 6;
  const unsigned short* wp = WpT + h * 48;
  const unsigned short* ab = attnT + ((long)(b*16 + h)) * 48 * 64;
  f32x4 acc[4][3] = {};
  #pragma unroll
  for (int kt = 0; kt < 64; kt += 32){
    bf16x8 bfr[3];
    #pragma unroll
    for (int ni = 0; ni < 3; ni++)
      bfr[ni] = *(const bf16x8*)(ab + (ni*16 + (lane & 15))*64 + kt + (lane >> 4)*8);
    #pragma unroll
    for (int mi = 0; mi < 4; mi++){
      const int j = j0 + w*64 + mi*16 + (lane & 15);
      bf16x8 a = *(const bf16x8*)(wp + (long)j*768 + kt + (lane >> 4)*8);
      #pragma unroll
      for (int ni = 0; ni < 3; ni++)
        acc[mi][ni] = __builtin_amdgcn_mfma_f32_16x16x32_bf16(a, bfr[ni], acc[mi][ni], 0, 0, 0);
    }
  }
  #pragma unroll
  for (int mi = 0; mi < 4; mi++)
    #pragma unroll
    for (int ni = 0; ni < 3; ni++)
      #pragma unroll
      for (int r = 0; r < 4; r++){
        const int j = j0 + w*64 + mi*16 + (lane >> 4)*4 + r;
        const int d = ni*16 + (lane & 15);
        WmodT[(long)b*589824 + (long)j*768 + h*48 + d] = f2bf(acc[mi][ni][r]);
      }
}

extern "C" void kernel_launch(void* const* d_in, const int* in_sizes, int n_in,
                              void* d_out, int out_size, void* d_ws, size_t ws_size,
                              hipStream_t stream)
{
  (void)in_sizes; (void)n_in; (void)out_size; (void)ws_size;
  const float* x      = (const float*)d_in[0];
  const float* w_qkv  = (const float*)d_in[1];
  const float* temp   = (const float*)d_in[2];
  const float* w_proj = (const float*)d_in[3];
  const float* b_proj = (const float*)d_in[4];
  float* outF = (float*)d_out;

  char* ws = (char*)d_ws;
  size_t off = 0;
  auto alloc = [&](size_t bytes)->char*{ char* p = ws + off; off += (bytes + 255) & ~(size_t)255; return p; };

  unsigned short* x_bf = (unsigned short*)alloc(50331648);            // [32768][768] bf16 (dead after gemm0)
  unsigned short* WT   = (unsigned short*)alloc(3538944);             // [2304][768] bf16
  unsigned short* WpT  = (unsigned short*)alloc(1179648);             // [768][768] bf16
  unsigned short* QT   = (unsigned short*)alloc(100663296);           // QT||KT [6144][4096] bf16 each
  unsigned short* KT   = QT + (long)6144 * 4096;
  unsigned short* V    = (unsigned short*)alloc(50331648);            // [32768][768] bf16
  float* nrmp          = (float*)alloc(12288L * 32 * 4);              // [12288 rows][32 chunks] f32

  // post-gemm0 buffers alias the dead x_bf region (50.3MB >> 9.4+4.7+0.8)
  unsigned short* WmodT = x_bf;                                       // [8][768][768] bf16
  float* Spart          = (float*)((char*)x_bf + 9437184);            // [4][128][48][48] f32
  unsigned short* attnT = (unsigned short*)((char*)x_bf + 9437184 + 4718592); // [128][48][64] bf16

  k_cvt<<<12288, 256, 0, stream>>>(x, x_bf, 25165824L);
  k_tconv<<<dim3(36, 12), 256, 0, stream>>>(w_qkv, WT, 768, 2304);
  k_tconv<<<dim3(12, 12), 256, 0, stream>>>(w_proj, WpT, 768, 768);
  k_gemm2<0><<<1152, 512, 0, stream>>>(x_bf, WT, QT, KT, V, nullptr, nullptr, nrmp);
  k_attn_part<<<dim3(128, 4), 256, 0, stream>>>(QT, KT, Spart);
  k_softmax<<<128, 64, 0, stream>>>(Spart, nrmp, temp, attnT);
  k_wmod2<<<dim3(3, 16, 8), 256, 0, stream>>>(WpT, attnT, WmodT);
  k_gemm2<1><<<384, 512, 0, stream>>>(V, WmodT, nullptr, nullptr, nullptr, outF, b_proj, nrmp);
}

// Round 6
// 259.755 us; speedup vs baseline: 1.2520x; 1.2520x over previous
//
#include <hip/hip_runtime.h>
#include <stdint.h>

typedef __attribute__((ext_vector_type(4))) float          f32x4;
typedef __attribute__((ext_vector_type(8))) short          bf16x8;
typedef __attribute__((ext_vector_type(8))) unsigned short u16x8;
typedef __attribute__((ext_vector_type(4))) unsigned short u16x4;

static __device__ __forceinline__ unsigned short f2bf(float f){
  uint32_t u = __builtin_bit_cast(uint32_t, f);
  u += 0x7FFFu + ((u >> 16) & 1u);          // RNE
  return (unsigned short)(u >> 16);
}
static __device__ __forceinline__ float bf2f(unsigned short h){
  uint32_t u = ((uint32_t)h) << 16;
  return __builtin_bit_cast(float, u);
}

// ---------------- elementwise convert f32 -> bf16 (8/thread) ----------------
__global__ void k_cvt(const float* __restrict__ in, unsigned short* __restrict__ out, long n){
  long i = ((long)blockIdx.x * blockDim.x + threadIdx.x) * 8;
  if (i >= n) return;
  const f32x4* p = (const f32x4*)(in + i);
  f32x4 a = p[0], b = p[1];
  u16x8 o;
  #pragma unroll
  for (int j = 0; j < 4; j++){ o[j] = f2bf(a[j]); o[4+j] = f2bf(b[j]); }
  *(u16x8*)(out + i) = o;
}

// ------- strided cvt: WvB[e][hd] = bf16(w_qkv[e][1536+hd]), 768x768 ---------
__global__ void k_cvtwv(const float* __restrict__ w, unsigned short* __restrict__ out){
  const long idx = ((long)blockIdx.x * blockDim.x + threadIdx.x) * 8;
  const int e = (int)(idx / 768), hd = (int)(idx - (long)e * 768);
  const float* s = w + (long)e * 2304 + 1536 + hd;
  f32x4 a = *(const f32x4*)s, b = *(const f32x4*)(s + 4);
  u16x8 o;
  #pragma unroll
  for (int j = 0; j < 4; j++){ o[j] = f2bf(a[j]); o[4+j] = f2bf(b[j]); }
  *(u16x8*)(out + idx) = o;
}

// ---------------- tiled transpose+convert: in[R][C] f32 -> out[C][R] bf16 ----
__global__ void k_tconv(const float* __restrict__ in, unsigned short* __restrict__ out, int R, int C){
  __shared__ float tl[64][65];
  const int c0 = blockIdx.x * 64, r0 = blockIdx.y * 64;
  const int t = threadIdx.x;
  {
    const int lr = t >> 2, lc = (t & 3) * 16;
    const f32x4* s = (const f32x4*)(in + (long)(r0 + lr) * C + c0 + lc);
    #pragma unroll
    for (int q = 0; q < 4; q++){
      f32x4 v = s[q];
      #pragma unroll
      for (int j = 0; j < 4; j++) tl[lr][lc + q*4 + j] = v[j];
    }
  }
  __syncthreads();
  {
    const int oc = t >> 2, orr = (t & 3) * 16;
    u16x8 o0, o1;
    #pragma unroll
    for (int i = 0; i < 8; i++){ o0[i] = f2bf(tl[orr + i][oc]); o1[i] = f2bf(tl[orr + 8 + i][oc]); }
    u16x8* dst = (u16x8*)(out + (long)(c0 + oc) * R + r0 + orr);
    dst[0] = o0; dst[1] = o1;
  }
}

// ================= 256x256 8-phase counted-vmcnt GEMM (r2 schedule) =========
static __device__ __forceinline__ void stage2(const unsigned short* __restrict__ G, int row0, int ke,
                                              char* lds_slot, int t){
  #pragma unroll
  for (int l = 0; l < 2; l++){
    const int r  = l*128 + (t >> 2);
    const int ko = (t & 3) ^ ((r ^ (r >> 2)) & 3);
    const char* src = (const char*)(G + (long)(row0 + r) * 768 + ke + ko * 8);
    char* dst = lds_slot + l*8192 + (t & 0x1C0) * 16;          // wave-uniform base
    __builtin_amdgcn_global_load_lds((const __attribute__((address_space(1))) unsigned int*)src,
                                     (__attribute__((address_space(3))) unsigned int*)dst, 16, 0, 0);
  }
}

static __device__ __forceinline__ bf16x8 ldfrag(const char* slot, int row, int ko){
  const int k2 = (ko ^ (row ^ (row >> 2))) & 3;
  return *(const bf16x8*)(slot + row*64 + k2*16);
}

#define PHASE(BUF, KK, MH, STAGE_STMT, WAIT_STMT) do {                         \
    bf16x8 af[4];                                                              \
    if (MH == 0) {                                                             \
      _Pragma("unroll")                                                        \
      for (int ni = 0; ni < 4; ni++)                                           \
        bq[ni] = ldfrag(sB[BUF][KK], wn*64 + ni*16 + arow, ko);                \
    }                                                                          \
    _Pragma("unroll")                                                          \
    for (int mi = 0; mi < 4; mi++)                                             \
      af[mi] = ldfrag(sA[BUF][KK], wm*128 + MH*64 + mi*16 + arow, ko);         \
    __builtin_amdgcn_s_barrier();                                              \
    __builtin_amdgcn_s_setprio(1);                                             \
    _Pragma("unroll")                                                          \
    for (int mi = 0; mi < 4; mi++)                                             \
      _Pragma("unroll")                                                        \
      for (int ni = 0; ni < 4; ni++)                                           \
        acc[MH*4+mi][ni] = __builtin_amdgcn_mfma_f32_16x16x32_bf16(            \
            af[mi], bq[ni], acc[MH*4+mi][ni], 0, 0, 0);                        \
    __builtin_amdgcn_s_setprio(0);                                             \
    STAGE_STMT;                                                                \
    WAIT_STMT;                                                                 \
    __builtin_amdgcn_s_barrier();                                              \
  } while(0)

// MODE 0: A=x_bf[32768][768], BT=WT[1536 rows q||k][768] -> QT/KT (transposed) + nrmp
// MODE 1: A=x_bf[32768][768], BT=WcombT[8][768][768] (batched) -> OUTF fp32 + bias
template<int MODE>
__global__ __launch_bounds__(512, 2)
void k_gemm2(const unsigned short* __restrict__ A, const unsigned short* __restrict__ BT,
             unsigned short* __restrict__ QT, unsigned short* __restrict__ KT,
             float* __restrict__ OUTF, const float* __restrict__ bias,
             float* __restrict__ nrmp)
{
  __shared__ __attribute__((aligned(16))) char lds[131072];
  constexpr int NT = (MODE == 0) ? 6 : 3;
  constexpr int NWG = NT * 128;
  const int o  = blockIdx.x;
  const int wg = (o & 7) * (NWG >> 3) + (o >> 3);          // bijective XCD swizzle
  const int jt = wg % NT, mt = wg / NT;
  const int m0 = mt * 256, j0 = jt * 256;
  const int t = threadIdx.x, lane = t & 63, w = t >> 6;
  const int wm = w >> 2, wn = w & 3;
  const int arow = lane & 15, ko = lane >> 4;
  const unsigned short* BTb = (MODE == 1) ? BT + ((long)(m0 >> 12)) * 768 * 768 : BT;

  char* const sA[2][2] = {{lds,           lds + 16384},
                          {lds + 65536,   lds + 65536 + 16384}};
  char* const sB[2][2] = {{lds + 32768,   lds + 49152},
                          {lds + 65536 + 32768, lds + 65536 + 49152}};

  f32x4 acc[8][4] = {};

  // prologue: tile0 fully; tile1 all but A1 (staged at iter0-ph1)
  stage2(BTb, j0, 0,   sB[0][0], t);
  stage2(A,   m0, 0,   sA[0][0], t);
  stage2(BTb, j0, 32,  sB[0][1], t);
  stage2(A,   m0, 32,  sA[0][1], t);
  stage2(BTb, j0, 64,  sB[1][0], t);
  stage2(A,   m0, 64,  sA[1][0], t);
  stage2(BTb, j0, 96,  sB[1][1], t);
  asm volatile("s_waitcnt vmcnt(6)" ::: "memory");
  __builtin_amdgcn_s_barrier();

  #pragma unroll 1
  for (int it = 0; it < 6; ++it){
    const int t1 = 2*it + 1, t2 = 2*it + 2, t3 = 2*it + 3;
    bf16x8 bq[4];
    // ---- tile T0 = 2*it (buf0) ----
    PHASE(0,0,0, { stage2(A, m0, t1*64+32, sA[1][1], t); }, ;);                  // A1(T1)
    PHASE(0,0,1, { if (t2 < 12) stage2(BTb, j0, t2*64,    sB[0][0], t); }, ;);   // B0(T2)
    PHASE(0,1,0, { if (t2 < 12) stage2(A,   m0, t2*64,    sA[0][0], t); }, ;);   // A0(T2)
    PHASE(0,1,1, { if (t2 < 12) stage2(BTb, j0, t2*64+32, sB[0][1], t); },
                 { if (it == 5) asm volatile("s_waitcnt vmcnt(0)" ::: "memory");
                   else         asm volatile("s_waitcnt vmcnt(6)" ::: "memory"); });
    // ---- tile T1 (buf1) ----
    PHASE(1,0,0, { if (t2 < 12) stage2(A,   m0, t2*64+32, sA[0][1], t); }, ;);   // A1(T2)
    PHASE(1,0,1, { if (t3 < 12) stage2(BTb, j0, t3*64,    sB[1][0], t); }, ;);   // B0(T3)
    PHASE(1,1,0, { if (t3 < 12) stage2(A,   m0, t3*64,    sA[1][0], t); }, ;);   // A0(T3)
    PHASE(1,1,1, { if (t3 < 12) stage2(BTb, j0, t3*64+32, sB[1][1], t); },
                 { if (it == 5) asm volatile("s_waitcnt vmcnt(0)" ::: "memory");
                   else         asm volatile("s_waitcnt vmcnt(6)" ::: "memory"); });
  }

  if (MODE == 0){
    const int b = m0 >> 12;
    const int nb = (m0 & 4095) + wm*128 + (lane >> 4)*4;
    #pragma unroll
    for (int mi = 0; mi < 8; mi++){
      #pragma unroll
      for (int ni = 0; ni < 4; ni++){
        const int jc = j0 + wn*64 + ni*16 + (lane & 15);
        const int s  = (jc >= 768);
        const int jl = jc - s * 768;
        const int h  = jl / 48;
        const int c  = jl - h * 48;
        unsigned short* dst = (s ? KT : QT) + (((long)(b*16 + h) * 48 + c) << 12) + nb + mi*16;
        u16x4 pk;
        #pragma unroll
        for (int r = 0; r < 4; r++) pk[r] = f2bf(acc[mi][ni][r]);
        *(u16x4*)dst = pk;
      }
    }
    // deterministic per-(row, 128-chunk) sum-of-squares partials (fp32, pre-bf16)
    const int chunk = ((m0 & 4095) >> 7) + wm;   // 32 chunks of 128 per batch-row
    #pragma unroll
    for (int ni = 0; ni < 4; ni++){
      float ss = 0.f;
      #pragma unroll
      for (int mi = 0; mi < 8; mi++)
        #pragma unroll
        for (int r = 0; r < 4; r++) ss += acc[mi][ni][r] * acc[mi][ni][r];
      ss += __shfl_xor(ss, 16);
      ss += __shfl_xor(ss, 32);
      if (lane < 16){
        const int jc = j0 + wn*64 + ni*16 + lane;
        const int s  = (jc >= 768);
        const int jl = jc - s * 768;
        const int h  = jl / 48;
        const int c  = jl - h * 48;
        const int prow = s*6144 + (b*16 + h)*48 + c;
        nrmp[(long)prow*32 + chunk] = ss;
      }
    }
  } else {
    #pragma unroll
    for (int mi = 0; mi < 8; mi++){
      #pragma unroll
      for (int ni = 0; ni < 4; ni++){
        const int jc = j0 + wn*64 + ni*16 + (lane & 15);
        const float bv = bias[jc];
        const long mr = (long)m0 + wm*128 + mi*16 + (lane >> 4)*4;
        #pragma unroll
        for (int r = 0; r < 4; r++) OUTF[(mr + r) * 768 + jc] = acc[mi][ni][r] + bv;
      }
    }
  }
}

// ---------------- S partials: per (bh, ksp) 48x48 over 1024 n ---------------
__global__ __launch_bounds__(256)
void k_attn_part(const unsigned short* __restrict__ QT, const unsigned short* __restrict__ KT,
                 float* __restrict__ Spart)
{
  __shared__ float Sl[4][2304];
  const int bh = blockIdx.x, ksp = blockIdx.y;
  const int t = threadIdx.x, lane = t & 63, w = t >> 6;
  const unsigned short* qb = QT + ((long)bh * 48 << 12);
  const unsigned short* kb = KT + ((long)bh * 48 << 12);
  const int n00 = ksp * 1024 + w * 256;
  f32x4 acc[3][3] = {};
  for (int kt = 0; kt < 256; kt += 32){
    bf16x8 af[3], bfr[3];
    #pragma unroll
    for (int ci = 0; ci < 3; ci++)
      af[ci]  = *(const bf16x8*)(qb + ((long)(ci*16 + (lane & 15)) << 12) + n00 + kt + (lane >> 4) * 8);
    #pragma unroll
    for (int di = 0; di < 3; di++)
      bfr[di] = *(const bf16x8*)(kb + ((long)(di*16 + (lane & 15)) << 12) + n00 + kt + (lane >> 4) * 8);
    #pragma unroll
    for (int ci = 0; ci < 3; ci++)
      #pragma unroll
      for (int di = 0; di < 3; di++)
        acc[ci][di] = __builtin_amdgcn_mfma_f32_16x16x32_bf16(af[ci], bfr[di], acc[ci][di], 0, 0, 0);
  }
  #pragma unroll
  for (int ci = 0; ci < 3; ci++)
    #pragma unroll
    for (int di = 0; di < 3; di++)
      #pragma unroll
      for (int r = 0; r < 4; r++)
        Sl[w][(ci*16 + (lane >> 4)*4 + r) * 48 + di*16 + (lane & 15)] = acc[ci][di][r];
  __syncthreads();
  float* outp = Spart + ((long)ksp * 128 + bh) * 2304;
  for (int idx = t; idx < 2304; idx += 256)
    outp[idx] = Sl[0][idx] + Sl[1][idx] + Sl[2][idx] + Sl[3][idx];
}

// --- reduce partials + norms, scale, softmax -> attnT bf16 [bh][48 d][64 c] --
__global__ void k_softmax(const float* __restrict__ Spart, const float* __restrict__ nrmp,
                          const float* __restrict__ temp, unsigned short* __restrict__ attnT)
{
  __shared__ float invq[48], invk[48];
  const int bh = blockIdx.x, h = bh & 15;
  const int c = threadIdx.x;   // 64 threads, 48 active
  if (c < 48){
    float sq = 0.f, sk = 0.f;
    const float* pq = nrmp + (long)(bh*48 + c) * 32;
    const float* pk = nrmp + (long)(6144 + bh*48 + c) * 32;
    #pragma unroll
    for (int i = 0; i < 32; i++){ sq += pq[i]; sk += pk[i]; }
    invq[c] = 1.0f / fmaxf(sqrtf(sq), 1e-12f);
    invk[c] = 1.0f / fmaxf(sqrtf(sk), 1e-12f);
  }
  __syncthreads();
  if (c < 48){
    const float scq = invq[c] * temp[h];
    float row[48];
    #pragma unroll
    for (int d = 0; d < 48; d++){
      long base = ((long)bh * 48 + c) * 48 + d;
      float v = Spart[base] + Spart[base + 128L*2304] + Spart[base + 256L*2304] + Spart[base + 384L*2304];
      row[d] = v * scq * invk[d];
    }
    float mx = -1e30f;
    #pragma unroll
    for (int d = 0; d < 48; d++) mx = fmaxf(mx, row[d]);
    float s = 0.f;
    #pragma unroll
    for (int d = 0; d < 48; d++){ row[d] = expf(row[d] - mx); s += row[d]; }
    const float inv = 1.0f / s;
    unsigned short* ob = attnT + (long)bh * 48 * 64;
    #pragma unroll
    for (int d = 0; d < 48; d++) ob[d*64 + c] = f2bf(row[d] * inv);
    u16x8 z = {};
    *(u16x8*)(ob + c*64 + 48) = z;
    *(u16x8*)(ob + c*64 + 56) = z;
  }
}

// --- WmodT[b][j][h*48+d] = sum_c attnT[bh][d][c] * WpT[j][h*48+c] (MFMA) -----
__global__ __launch_bounds__(256)
void k_wmod2(const unsigned short* __restrict__ WpT, const unsigned short* __restrict__ attnT,
             unsigned short* __restrict__ WmodT)
{
  const int j0 = blockIdx.x * 256, h = blockIdx.y, b = blockIdx.z;
  const int t = threadIdx.x, lane = t & 63, w = t >> 6;
  const unsigned short* wp = WpT + h * 48;
  const unsigned short* ab = attnT + ((long)(b*16 + h)) * 48 * 64;
  f32x4 acc[4][3] = {};
  #pragma unroll
  for (int kt = 0; kt < 64; kt += 32){
    bf16x8 bfr[3];
    #pragma unroll
    for (int ni = 0; ni < 3; ni++)
      bfr[ni] = *(const bf16x8*)(ab + (ni*16 + (lane & 15))*64 + kt + (lane >> 4)*8);
    #pragma unroll
    for (int mi = 0; mi < 4; mi++){
      const int j = j0 + w*64 + mi*16 + (lane & 15);
      bf16x8 a = *(const bf16x8*)(wp + (long)j*768 + kt + (lane >> 4)*8);
      #pragma unroll
      for (int ni = 0; ni < 3; ni++)
        acc[mi][ni] = __builtin_amdgcn_mfma_f32_16x16x32_bf16(a, bfr[ni], acc[mi][ni], 0, 0, 0);
    }
  }
  #pragma unroll
  for (int mi = 0; mi < 4; mi++)
    #pragma unroll
    for (int ni = 0; ni < 3; ni++)
      #pragma unroll
      for (int r = 0; r < 4; r++){
        const int j = j0 + w*64 + mi*16 + (lane >> 4)*4 + r;
        const int d = ni*16 + (lane & 15);
        WmodT[(long)b*589824 + (long)j*768 + h*48 + d] = f2bf(acc[mi][ni][r]);
      }
}

// --- WcombT[6144 rows=b*768+j][768 e] = WmodT[row][hd] @ WvB[e][hd] (128² tile)
__global__ __launch_bounds__(256)
void k_comb(const unsigned short* __restrict__ A, const unsigned short* __restrict__ BT,
            unsigned short* __restrict__ OUT)
{
  __shared__ unsigned short As[128 * 32];
  __shared__ unsigned short Bs[128 * 32];
  const int m0 = blockIdx.y * 128;
  const int j0 = blockIdx.x * 128;
  const int t = threadIdx.x;
  const int lane = t & 63;
  const int w = t >> 6, wm = w >> 1, wn = w & 1;

  f32x4 acc[4][4] = {};

  for (int kt = 0; kt < 768; kt += 32){
    if (kt) __syncthreads();
    #pragma unroll
    for (int i = 0; i < 2; i++){
      const char* ga = (const char*)A  + (long)(m0 + i*64 + (t >> 2)) * 1536 + kt*2 + (t & 3) * 16;
      const char* gb = (const char*)BT + (long)(j0 + i*64 + (t >> 2)) * 1536 + kt*2 + (t & 3) * 16;
      char* la = (char*)As + i*4096 + (t & 0xC0) * 16;
      char* lb = (char*)Bs + i*4096 + (t & 0xC0) * 16;
      __builtin_amdgcn_global_load_lds((const __attribute__((address_space(1))) unsigned int*)ga,
                                       (__attribute__((address_space(3))) unsigned int*)la, 16, 0, 0);
      __builtin_amdgcn_global_load_lds((const __attribute__((address_space(1))) unsigned int*)gb,
                                       (__attribute__((address_space(3))) unsigned int*)lb, 16, 0, 0);
    }
    __syncthreads();
    bf16x8 af[4], bfr[4];
    #pragma unroll
    for (int mi = 0; mi < 4; mi++)
      af[mi]  = *(const bf16x8*)&As[(wm*64 + mi*16 + (lane & 15)) * 32 + (lane >> 4) * 8];
    #pragma unroll
    for (int ni = 0; ni < 4; ni++)
      bfr[ni] = *(const bf16x8*)&Bs[(wn*64 + ni*16 + (lane & 15)) * 32 + (lane >> 4) * 8];
    #pragma unroll
    for (int mi = 0; mi < 4; mi++)
      #pragma unroll
      for (int ni = 0; ni < 4; ni++)
        acc[mi][ni] = __builtin_amdgcn_mfma_f32_16x16x32_bf16(af[mi], bfr[ni], acc[mi][ni], 0, 0, 0);
  }

  #pragma unroll
  for (int mi = 0; mi < 4; mi++)
    #pragma unroll
    for (int ni = 0; ni < 4; ni++){
      const int jc = j0 + wn*64 + ni*16 + (lane & 15);
      const long mr = (long)m0 + wm*64 + mi*16 + (lane >> 4) * 4;
      #pragma unroll
      for (int r = 0; r < 4; r++) OUT[(mr + r) * 768 + jc] = f2bf(acc[mi][ni][r]);
    }
}

extern "C" void kernel_launch(void* const* d_in, const int* in_sizes, int n_in,
                              void* d_out, int out_size, void* d_ws, size_t ws_size,
                              hipStream_t stream)
{
  (void)in_sizes; (void)n_in; (void)out_size; (void)ws_size;
  const float* x      = (const float*)d_in[0];
  const float* w_qkv  = (const float*)d_in[1];
  const float* temp   = (const float*)d_in[2];
  const float* w_proj = (const float*)d_in[3];
  const float* b_proj = (const float*)d_in[4];
  float* outF = (float*)d_out;

  char* ws = (char*)d_ws;
  size_t off = 0;
  auto alloc = [&](size_t bytes)->char*{ char* p = ws + off; off += (bytes + 255) & ~(size_t)255; return p; };

  unsigned short* x_bf  = (unsigned short*)alloc(50331648);           // [32768][768] bf16
  unsigned short* WT    = (unsigned short*)alloc(3538944);            // [2304][768] bf16 (rows 0..1535 used)
  unsigned short* WpT   = (unsigned short*)alloc(1179648);            // [768][768] bf16
  unsigned short* WvB   = (unsigned short*)alloc(1179648);            // [768 e][768 hd] bf16
  unsigned short* QT    = (unsigned short*)alloc(100663296);          // QT||KT [6144][4096] bf16 each
  unsigned short* KT    = QT + (long)6144 * 4096;
  float* nrmp           = (float*)alloc(12288L * 32 * 4);             // [12288 rows][32 chunks] f32
  float* Spart          = (float*)alloc(4L * 128 * 2304 * 4);         // [4][128][48][48] f32
  unsigned short* attnT = (unsigned short*)alloc(128L * 48 * 64 * 2); // [128][48 d][64 c] bf16
  unsigned short* WmodT = (unsigned short*)alloc(9437184);            // [8][768 j][768 hd] bf16
  unsigned short* WcombT= (unsigned short*)alloc(9437184);            // [8][768 j][768 e] bf16

  k_cvt<<<12288, 256, 0, stream>>>(x, x_bf, 25165824L);
  k_tconv<<<dim3(36, 12), 256, 0, stream>>>(w_qkv, WT, 768, 2304);
  k_tconv<<<dim3(12, 12), 256, 0, stream>>>(w_proj, WpT, 768, 768);
  k_cvtwv<<<288, 256, 0, stream>>>(w_qkv, WvB);
  k_gemm2<0><<<768, 512, 0, stream>>>(x_bf, WT, QT, KT, nullptr, nullptr, nrmp);
  k_attn_part<<<dim3(128, 4), 256, 0, stream>>>(QT, KT, Spart);
  k_softmax<<<128, 64, 0, stream>>>(Spart, nrmp, temp, attnT);
  k_wmod2<<<dim3(3, 16, 8), 256, 0, stream>>>(WpT, attnT, WmodT);
  k_comb<<<dim3(6, 48), 256, 0, stream>>>(WmodT, WvB, WcombT);
  k_gemm2<1><<<384, 512, 0, stream>>>(x_bf, WcombT, nullptr, nullptr, outF, b_proj, nullptr);
}

// Round 7
// 253.210 us; speedup vs baseline: 1.2843x; 1.0258x over previous
//
#include <hip/hip_runtime.h>
#include <stdint.h>

typedef __attribute__((ext_vector_type(4))) float          f32x4;
typedef __attribute__((ext_vector_type(8))) short          bf16x8;
typedef __attribute__((ext_vector_type(8))) unsigned short u16x8;
typedef __attribute__((ext_vector_type(4))) unsigned short u16x4;

static __device__ __forceinline__ unsigned short f2bf(float f){
  uint32_t u = __builtin_bit_cast(uint32_t, f);
  u += 0x7FFFu + ((u >> 16) & 1u);          // RNE
  return (unsigned short)(u >> 16);
}
static __device__ __forceinline__ float bf2f(unsigned short h){
  uint32_t u = ((uint32_t)h) << 16;
  return __builtin_bit_cast(float, u);
}

// ---------------- elementwise convert f32 -> bf16 (8/thread) ----------------
__global__ void k_cvt(const float* __restrict__ in, unsigned short* __restrict__ out, long n){
  long i = ((long)blockIdx.x * blockDim.x + threadIdx.x) * 8;
  if (i >= n) return;
  const f32x4* p = (const f32x4*)(in + i);
  f32x4 a = p[0], b = p[1];
  u16x8 o;
  #pragma unroll
  for (int j = 0; j < 4; j++){ o[j] = f2bf(a[j]); o[4+j] = f2bf(b[j]); }
  *(u16x8*)(out + i) = o;
}

// ------- strided cvt: WvB[e][hd] = bf16(w_qkv[e][1536+hd]), 768x768 ---------
__global__ void k_cvtwv(const float* __restrict__ w, unsigned short* __restrict__ out){
  const long idx = ((long)blockIdx.x * blockDim.x + threadIdx.x) * 8;
  const int e = (int)(idx / 768), hd = (int)(idx - (long)e * 768);
  const float* s = w + (long)e * 2304 + 1536 + hd;
  f32x4 a = *(const f32x4*)s, b = *(const f32x4*)(s + 4);
  u16x8 o;
  #pragma unroll
  for (int j = 0; j < 4; j++){ o[j] = f2bf(a[j]); o[4+j] = f2bf(b[j]); }
  *(u16x8*)(out + idx) = o;
}

// ---------------- tiled transpose+convert: in[R][C] f32 -> out[C][R] bf16 ----
__global__ void k_tconv(const float* __restrict__ in, unsigned short* __restrict__ out, int R, int C){
  __shared__ float tl[64][65];
  const int c0 = blockIdx.x * 64, r0 = blockIdx.y * 64;
  const int t = threadIdx.x;
  {
    const int lr = t >> 2, lc = (t & 3) * 16;
    const f32x4* s = (const f32x4*)(in + (long)(r0 + lr) * C + c0 + lc);
    #pragma unroll
    for (int q = 0; q < 4; q++){
      f32x4 v = s[q];
      #pragma unroll
      for (int j = 0; j < 4; j++) tl[lr][lc + q*4 + j] = v[j];
    }
  }
  __syncthreads();
  {
    const int oc = t >> 2, orr = (t & 3) * 16;
    u16x8 o0, o1;
    #pragma unroll
    for (int i = 0; i < 8; i++){ o0[i] = f2bf(tl[orr + i][oc]); o1[i] = f2bf(tl[orr + 8 + i][oc]); }
    u16x8* dst = (u16x8*)(out + (long)(c0 + oc) * R + r0 + orr);
    dst[0] = o0; dst[1] = o1;
  }
}

// ============ 128x256 BK=32 ring-3 counted-vmcnt GEMM, 2 blocks/CU ==========
// Phase (1 per K-tile) = {8 ds_read_b128; bar; 16 MFMA; stage tile t+2 (3
// loads); vmcnt(3); bar}. Ring-3 LDS 72KB -> 2 blocks/CU hide each other's
// stalls. Gate completes tile t+1, leaves t+2 in flight.

static __device__ __forceinline__ void stageA(const unsigned short* __restrict__ G, int row0, int ke,
                                              char* slot, int t){
  const int r  = t >> 2;
  const int ko = (t & 3) ^ ((r ^ (r >> 2)) & 3);
  const char* src = (const char*)(G + (long)(row0 + r) * 768 + ke + ko * 8);
  char* dst = slot + (t & 0x1C0) * 16;                       // wave-uniform base
  __builtin_amdgcn_global_load_lds((const __attribute__((address_space(1))) unsigned int*)src,
                                   (__attribute__((address_space(3))) unsigned int*)dst, 16, 0, 0);
}
static __device__ __forceinline__ void stageB(const unsigned short* __restrict__ G, int row0, int ke,
                                              char* slot, int t){
  #pragma unroll
  for (int l = 0; l < 2; l++){
    const int r  = l*128 + (t >> 2);
    const int ko = (t & 3) ^ ((r ^ (r >> 2)) & 3);
    const char* src = (const char*)(G + (long)(row0 + r) * 768 + ke + ko * 8);
    char* dst = slot + l*8192 + (t & 0x1C0) * 16;
    __builtin_amdgcn_global_load_lds((const __attribute__((address_space(1))) unsigned int*)src,
                                     (__attribute__((address_space(3))) unsigned int*)dst, 16, 0, 0);
  }
}

static __device__ __forceinline__ bf16x8 ldfrag(const char* slot, int row, int ko){
  const int k2 = (ko ^ (row ^ (row >> 2))) & 3;
  return *(const bf16x8*)(slot + row*64 + k2*16);
}

#define VM3 asm volatile("s_waitcnt vmcnt(3)" ::: "memory")
#define VM0 asm volatile("s_waitcnt vmcnt(0)" ::: "memory")

#define PHASE1(CUR, STAGE_STMT, WAIT_STMT) do {                                \
    bf16x8 af[4], bq[4];                                                       \
    _Pragma("unroll")                                                          \
    for (int ni = 0; ni < 4; ni++)                                             \
      bq[ni] = ldfrag(sB[CUR], wn*64 + ni*16 + arow, ko);                      \
    _Pragma("unroll")                                                          \
    for (int mi = 0; mi < 4; mi++)                                             \
      af[mi] = ldfrag(sA[CUR], wm*64 + mi*16 + arow, ko);                      \
    __builtin_amdgcn_s_barrier();                                              \
    __builtin_amdgcn_s_setprio(1);                                             \
    _Pragma("unroll")                                                          \
    for (int mi = 0; mi < 4; mi++)                                             \
      _Pragma("unroll")                                                        \
      for (int ni = 0; ni < 4; ni++)                                           \
        acc[mi][ni] = __builtin_amdgcn_mfma_f32_16x16x32_bf16(                 \
            af[mi], bq[ni], acc[mi][ni], 0, 0, 0);                             \
    __builtin_amdgcn_s_setprio(0);                                             \
    STAGE_STMT;                                                                \
    WAIT_STMT;                                                                 \
    __builtin_amdgcn_s_barrier();                                              \
  } while(0)

// MODE 0: A=x_bf[32768][768], BT=WT[1536 q||k][768] -> QT/KT (transposed) + nrmp
// MODE 1: A=x_bf[32768][768], BT=WcombT[8][768][768] (batched) -> OUTF + bias
template<int MODE>
__global__ __launch_bounds__(512, 4)
void k_gemm3(const unsigned short* __restrict__ A, const unsigned short* __restrict__ BT,
             unsigned short* __restrict__ QT, unsigned short* __restrict__ KT,
             float* __restrict__ OUTF, const float* __restrict__ bias,
             float* __restrict__ nrmp)
{
  __shared__ __attribute__((aligned(16))) char lds[73728];
  constexpr int NT = (MODE == 0) ? 6 : 3;
  constexpr int NWG = 256 * NT;
  const int o  = blockIdx.x;
  const int wg = (o & 7) * (NWG >> 3) + (o >> 3);          // bijective XCD swizzle
  const int jt = wg % NT, mt = wg / NT;
  const int m0 = mt * 128, j0 = jt * 256;
  const int t = threadIdx.x, lane = t & 63, w = t >> 6;
  const int wm = w >> 2, wn = w & 3;
  const int arow = lane & 15, ko = lane >> 4;
  const unsigned short* BTb = (MODE == 1) ? BT + ((long)(m0 >> 12)) * 768 * 768 : BT;

  char* const sA[3] = {lds,          lds + 8192,          lds + 16384};
  char* const sB[3] = {lds + 24576,  lds + 24576 + 16384, lds + 24576 + 32768};

  f32x4 acc[4][4] = {};

  // prologue: tiles 0,1 (3 loads each); vmcnt(3) completes tile 0
  stageA(A, m0, 0,  sA[0], t);  stageB(BTb, j0, 0,  sB[0], t);
  stageA(A, m0, 32, sA[1], t);  stageB(BTb, j0, 32, sB[1], t);
  VM3;
  __builtin_amdgcn_s_barrier();

  #pragma unroll 1
  for (int g = 0; g < 7; ++g){                             // tiles 0..20
    const int ke2 = g * 96;
    PHASE1(0, { stageA(A, m0, ke2+64,  sA[2], t); stageB(BTb, j0, ke2+64,  sB[2], t); }, VM3);
    PHASE1(1, { stageA(A, m0, ke2+96,  sA[0], t); stageB(BTb, j0, ke2+96,  sB[0], t); }, VM3);
    PHASE1(2, { stageA(A, m0, ke2+128, sA[1], t); stageB(BTb, j0, ke2+128, sB[1], t); }, VM3);
  }
  // tail: tiles 21,22,23
  PHASE1(0, { stageA(A, m0, 736, sA[2], t); stageB(BTb, j0, 736, sB[2], t); }, VM3);
  PHASE1(1, { ; }, VM0);
  PHASE1(2, { ; }, ;);

  if (MODE == 0){
    const int b = m0 >> 12;
    const int nb = (m0 & 4095) + wm*64 + (lane >> 4)*4;
    #pragma unroll
    for (int mi = 0; mi < 4; mi++){
      #pragma unroll
      for (int ni = 0; ni < 4; ni++){
        const int jc = j0 + wn*64 + ni*16 + (lane & 15);
        const int s  = (jc >= 768);
        const int jl = jc - s * 768;
        const int h  = jl / 48;
        const int c  = jl - h * 48;
        unsigned short* dst = (s ? KT : QT) + (((long)(b*16 + h) * 48 + c) << 12) + nb + mi*16;
        u16x4 pk;
        #pragma unroll
        for (int r = 0; r < 4; r++) pk[r] = f2bf(acc[mi][ni][r]);
        *(u16x4*)dst = pk;
      }
    }
    // per-(row, 64-chunk) sum-of-squares partials (fp32, pre-bf16)
    const int chunk = ((m0 & 4095) >> 6) + wm;   // 64 chunks of 64 per batch-row
    #pragma unroll
    for (int ni = 0; ni < 4; ni++){
      float ss = 0.f;
      #pragma unroll
      for (int mi = 0; mi < 4; mi++)
        #pragma unroll
        for (int r = 0; r < 4; r++) ss += acc[mi][ni][r] * acc[mi][ni][r];
      ss += __shfl_xor(ss, 16);
      ss += __shfl_xor(ss, 32);
      if (lane < 16){
        const int jc = j0 + wn*64 + ni*16 + lane;
        const int s  = (jc >= 768);
        const int jl = jc - s * 768;
        const int h  = jl / 48;
        const int c  = jl - h * 48;
        const int prow = s*6144 + (b*16 + h)*48 + c;
        nrmp[(long)prow*64 + chunk] = ss;
      }
    }
  } else {
    #pragma unroll
    for (int mi = 0; mi < 4; mi++){
      #pragma unroll
      for (int ni = 0; ni < 4; ni++){
        const int jc = j0 + wn*64 + ni*16 + (lane & 15);
        const float bv = bias[jc];
        const long mr = (long)m0 + wm*64 + mi*16 + (lane >> 4)*4;
        #pragma unroll
        for (int r = 0; r < 4; r++) OUTF[(mr + r) * 768 + jc] = acc[mi][ni][r] + bv;
      }
    }
  }
}

// ---------------- S partials: per (bh, ksp) 48x48 over 1024 n ---------------
__global__ __launch_bounds__(256)
void k_attn_part(const unsigned short* __restrict__ QT, const unsigned short* __restrict__ KT,
                 float* __restrict__ Spart)
{
  __shared__ float Sl[4][2304];
  const int bh = blockIdx.x, ksp = blockIdx.y;
  const int t = threadIdx.x, lane = t & 63, w = t >> 6;
  const unsigned short* qb = QT + ((long)bh * 48 << 12);
  const unsigned short* kb = KT + ((long)bh * 48 << 12);
  const int n00 = ksp * 1024 + w * 256;
  f32x4 acc[3][3] = {};
  for (int kt = 0; kt < 256; kt += 32){
    bf16x8 af[3], bfr[3];
    #pragma unroll
    for (int ci = 0; ci < 3; ci++)
      af[ci]  = *(const bf16x8*)(qb + ((long)(ci*16 + (lane & 15)) << 12) + n00 + kt + (lane >> 4) * 8);
    #pragma unroll
    for (int di = 0; di < 3; di++)
      bfr[di] = *(const bf16x8*)(kb + ((long)(di*16 + (lane & 15)) << 12) + n00 + kt + (lane >> 4) * 8);
    #pragma unroll
    for (int ci = 0; ci < 3; ci++)
      #pragma unroll
      for (int di = 0; di < 3; di++)
        acc[ci][di] = __builtin_amdgcn_mfma_f32_16x16x32_bf16(af[ci], bfr[di], acc[ci][di], 0, 0, 0);
  }
  #pragma unroll
  for (int ci = 0; ci < 3; ci++)
    #pragma unroll
    for (int di = 0; di < 3; di++)
      #pragma unroll
      for (int r = 0; r < 4; r++)
        Sl[w][(ci*16 + (lane >> 4)*4 + r) * 48 + di*16 + (lane & 15)] = acc[ci][di][r];
  __syncthreads();
  float* outp = Spart + ((long)ksp * 128 + bh) * 2304;
  for (int idx = t; idx < 2304; idx += 256)
    outp[idx] = Sl[0][idx] + Sl[1][idx] + Sl[2][idx] + Sl[3][idx];
}

// --- reduce partials + norms, scale, softmax -> attnT bf16 [bh][48 d][64 c] --
__global__ void k_softmax(const float* __restrict__ Spart, const float* __restrict__ nrmp,
                          const float* __restrict__ temp, unsigned short* __restrict__ attnT)
{
  __shared__ float invq[48], invk[48];
  const int bh = blockIdx.x, h = bh & 15;
  const int c = threadIdx.x;   // 64 threads, 48 active
  if (c < 48){
    float sq = 0.f, sk = 0.f;
    const float* pq = nrmp + (long)(bh*48 + c) * 64;
    const float* pk = nrmp + (long)(6144 + bh*48 + c) * 64;
    #pragma unroll
    for (int i = 0; i < 64; i++){ sq += pq[i]; sk += pk[i]; }
    invq[c] = 1.0f / fmaxf(sqrtf(sq), 1e-12f);
    invk[c] = 1.0f / fmaxf(sqrtf(sk), 1e-12f);
  }
  __syncthreads();
  if (c < 48){
    const float scq = invq[c] * temp[h];
    float row[48];
    #pragma unroll
    for (int d = 0; d < 48; d++){
      long base = ((long)bh * 48 + c) * 48 + d;
      float v = Spart[base] + Spart[base + 128L*2304] + Spart[base + 256L*2304] + Spart[base + 384L*2304];
      row[d] = v * scq * invk[d];
    }
    float mx = -1e30f;
    #pragma unroll
    for (int d = 0; d < 48; d++) mx = fmaxf(mx, row[d]);
    float s = 0.f;
    #pragma unroll
    for (int d = 0; d < 48; d++){ row[d] = expf(row[d] - mx); s += row[d]; }
    const float inv = 1.0f / s;
    unsigned short* ob = attnT + (long)bh * 48 * 64;
    #pragma unroll
    for (int d = 0; d < 48; d++) ob[d*64 + c] = f2bf(row[d] * inv);
    u16x8 z = {};
    *(u16x8*)(ob + c*64 + 48) = z;
    *(u16x8*)(ob + c*64 + 56) = z;
  }
}

// --- WmodT[b][j][h*48+d] = sum_c attnT[bh][d][c] * WpT[j][h*48+c] (MFMA) -----
__global__ __launch_bounds__(256)
void k_wmod2(const unsigned short* __restrict__ WpT, const unsigned short* __restrict__ attnT,
             unsigned short* __restrict__ WmodT)
{
  const int j0 = blockIdx.x * 256, h = blockIdx.y, b = blockIdx.z;
  const int t = threadIdx.x, lane = t & 63, w = t >> 6;
  const unsigned short* wp = WpT + h * 48;
  const unsigned short* ab = attnT + ((long)(b*16 + h)) * 48 * 64;
  f32x4 acc[4][3] = {};
  #pragma unroll
  for (int kt = 0; kt < 64; kt += 32){
    bf16x8 bfr[3];
    #pragma unroll
    for (int ni = 0; ni < 3; ni++)
      bfr[ni] = *(const bf16x8*)(ab + (ni*16 + (lane & 15))*64 + kt + (lane >> 4)*8);
    #pragma unroll
    for (int mi = 0; mi < 4; mi++){
      const int j = j0 + w*64 + mi*16 + (lane & 15);
      bf16x8 a = *(const bf16x8*)(wp + (long)j*768 + kt + (lane >> 4)*8);
      #pragma unroll
      for (int ni = 0; ni < 3; ni++)
        acc[mi][ni] = __builtin_amdgcn_mfma_f32_16x16x32_bf16(a, bfr[ni], acc[mi][ni], 0, 0, 0);
    }
  }
  #pragma unroll
  for (int mi = 0; mi < 4; mi++)
    #pragma unroll
    for (int ni = 0; ni < 3; ni++)
      #pragma unroll
      for (int r = 0; r < 4; r++){
        const int j = j0 + w*64 + mi*16 + (lane >> 4)*4 + r;
        const int d = ni*16 + (lane & 15);
        WmodT[(long)b*589824 + (long)j*768 + h*48 + d] = f2bf(acc[mi][ni][r]);
      }
}

// --- WcombT[6144 rows=b*768+j][768 e] = WmodT[row][hd] @ WvB[e][hd] (128² tile)
__global__ __launch_bounds__(256)
void k_comb(const unsigned short* __restrict__ A, const unsigned short* __restrict__ BT,
            unsigned short* __restrict__ OUT)
{
  __shared__ unsigned short As[128 * 32];
  __shared__ unsigned short Bs[128 * 32];
  const int m0 = blockIdx.y * 128;
  const int j0 = blockIdx.x * 128;
  const int t = threadIdx.x;
  const int lane = t & 63;
  const int w = t >> 6, wm = w >> 1, wn = w & 1;

  f32x4 acc[4][4] = {};

  for (int kt = 0; kt < 768; kt += 32){
    if (kt) __syncthreads();
    #pragma unroll
    for (int i = 0; i < 2; i++){
      const char* ga = (const char*)A  + (long)(m0 + i*64 + (t >> 2)) * 1536 + kt*2 + (t & 3) * 16;
      const char* gb = (const char*)BT + (long)(j0 + i*64 + (t >> 2)) * 1536 + kt*2 + (t & 3) * 16;
      char* la = (char*)As + i*4096 + (t & 0xC0) * 16;
      char* lb = (char*)Bs + i*4096 + (t & 0xC0) * 16;
      __builtin_amdgcn_global_load_lds((const __attribute__((address_space(1))) unsigned int*)ga,
                                       (__attribute__((address_space(3))) unsigned int*)la, 16, 0, 0);
      __builtin_amdgcn_global_load_lds((const __attribute__((address_space(1))) unsigned int*)gb,
                                       (__attribute__((address_space(3))) unsigned int*)lb, 16, 0, 0);
    }
    __syncthreads();
    bf16x8 af[4], bfr[4];
    #pragma unroll
    for (int mi = 0; mi < 4; mi++)
      af[mi]  = *(const bf16x8*)&As[(wm*64 + mi*16 + (lane & 15)) * 32 + (lane >> 4) * 8];
    #pragma unroll
    for (int ni = 0; ni < 4; ni++)
      bfr[ni] = *(const bf16x8*)&Bs[(wn*64 + ni*16 + (lane & 15)) * 32 + (lane >> 4) * 8];
    #pragma unroll
    for (int mi = 0; mi < 4; mi++)
      #pragma unroll
      for (int ni = 0; ni < 4; ni++)
        acc[mi][ni] = __builtin_amdgcn_mfma_f32_16x16x32_bf16(af[mi], bfr[ni], acc[mi][ni], 0, 0, 0);
  }

  #pragma unroll
  for (int mi = 0; mi < 4; mi++)
    #pragma unroll
    for (int ni = 0; ni < 4; ni++){
      const int jc = j0 + wn*64 + ni*16 + (lane & 15);
      const long mr = (long)m0 + wm*64 + mi*16 + (lane >> 4) * 4;
      #pragma unroll
      for (int r = 0; r < 4; r++) OUT[(mr + r) * 768 + jc] = f2bf(acc[mi][ni][r]);
    }
}

extern "C" void kernel_launch(void* const* d_in, const int* in_sizes, int n_in,
                              void* d_out, int out_size, void* d_ws, size_t ws_size,
                              hipStream_t stream)
{
  (void)in_sizes; (void)n_in; (void)out_size; (void)ws_size;
  const float* x      = (const float*)d_in[0];
  const float* w_qkv  = (const float*)d_in[1];
  const float* temp   = (const float*)d_in[2];
  const float* w_proj = (const float*)d_in[3];
  const float* b_proj = (const float*)d_in[4];
  float* outF = (float*)d_out;

  char* ws = (char*)d_ws;
  size_t off = 0;
  auto alloc = [&](size_t bytes)->char*{ char* p = ws + off; off += (bytes + 255) & ~(size_t)255; return p; };

  unsigned short* x_bf  = (unsigned short*)alloc(50331648);           // [32768][768] bf16
  unsigned short* WT    = (unsigned short*)alloc(3538944);            // [2304][768] bf16 (rows 0..1535 used)
  unsigned short* WpT   = (unsigned short*)alloc(1179648);            // [768][768] bf16
  unsigned short* WvB   = (unsigned short*)alloc(1179648);            // [768 e][768 hd] bf16
  unsigned short* QT    = (unsigned short*)alloc(100663296);          // QT||KT [6144][4096] bf16 each
  unsigned short* KT    = QT + (long)6144 * 4096;
  float* nrmp           = (float*)alloc(12288L * 64 * 4);             // [12288 rows][64 chunks] f32
  float* Spart          = (float*)alloc(4L * 128 * 2304 * 4);         // [4][128][48][48] f32
  unsigned short* attnT = (unsigned short*)alloc(128L * 48 * 64 * 2); // [128][48 d][64 c] bf16
  unsigned short* WmodT = (unsigned short*)alloc(9437184);            // [8][768 j][768 hd] bf16
  unsigned short* WcombT= (unsigned short*)alloc(9437184);            // [8][768 j][768 e] bf16

  k_cvt<<<12288, 256, 0, stream>>>(x, x_bf, 25165824L);
  k_tconv<<<dim3(36, 12), 256, 0, stream>>>(w_qkv, WT, 768, 2304);
  k_tconv<<<dim3(12, 12), 256, 0, stream>>>(w_proj, WpT, 768, 768);
  k_cvtwv<<<288, 256, 0, stream>>>(w_qkv, WvB);
  k_gemm3<0><<<1536, 512, 0, stream>>>(x_bf, WT, QT, KT, nullptr, nullptr, nrmp);
  k_attn_part<<<dim3(128, 4), 256, 0, stream>>>(QT, KT, Spart);
  k_softmax<<<128, 64, 0, stream>>>(Spart, nrmp, temp, attnT);
  k_wmod2<<<dim3(3, 16, 8), 256, 0, stream>>>(WpT, attnT, WmodT);
  k_comb<<<dim3(6, 48), 256, 0, stream>>>(WmodT, WvB, WcombT);
  k_gemm3<1><<<768, 512, 0, stream>>>(x_bf, WcombT, nullptr, nullptr, outF, b_proj, nullptr);
}